// Round 1
// baseline (4168.629 us; speedup 1.0000x reference)
//
#include <hip/hip_runtime.h>

#define NQ 273
#define NB 2

typedef float f4 __attribute__((ext_vector_type(4)));

// ---------------- compile-time GA tables (Cl(3,0,1) PGA, 16 blades) ----------------
struct GATab {
  int qi[NQ]; int qj[NQ]; int qk[NQ];
  float qs[NQ];
  int qgp[NQ];
  int qpath[NQ];
  int ngp, njp, nq;
};

constexpr int popc4(int m){ int c=0; for(int b=0;b<5;++b) c+=(m>>b)&1; return c; }
constexpr int swap_par(int a,int b){ int s=0; a>>=1; while(a){ s+=popc4(a&b); a>>=1; } return s&1; }

constexpr GATab make_tab(){
  GATab t{};
  int bladeOf[16]={}; int idxOf[16]={};
  { int p=0;
    for(int g=0; g<=4; ++g)
      for(int m=0; m<16; ++m)
        if(popc4(m)==g){ bladeOf[p]=m; idxOf[m]=p; ++p; }
  }
  int grade[16]={};
  for(int j=0;j<16;++j) grade[j]=popc4(bladeOf[j]);
  bool gpp[125]={}; bool jpp[125]={};
  for(int j=0;j<16;++j) for(int k=0;k<16;++k){
    int mj=bladeOf[j], mk=bladeOf[k];
    if(!(mj&mk&1)){ int i=idxOf[mj^mk]; gpp[(grade[i]*5+grade[j])*5+grade[k]]=true; }
    int cj=15^mj, ck=15^mk;
    if(!(cj&ck)){ int r=mj&mk; int i=idxOf[r]; jpp[(grade[i]*5+grade[j])*5+grade[k]]=true; }
  }
  int gpidx[125]={}; int jpidx[125]={};
  { int c=0; for(int u=0;u<125;++u){ gpidx[u] = gpp[u]? c++ : -1; } t.ngp=c; }
  { int c=0; for(int u=0;u<125;++u){ jpidx[u] = jpp[u]? c++ : -1; } t.njp=c; }
  int q=0;
  for(int j=0;j<16;++j) for(int k=0;k<16;++k){
    int mj=bladeOf[j], mk=bladeOf[k];
    if(!(mj&mk&1)){
      int i=idxOf[mj^mk];
      t.qi[q]=i; t.qj[q]=j; t.qk[q]=k;
      t.qs[q] = swap_par(mj,mk) ? -1.0f : 1.0f;
      t.qgp[q]=1;
      t.qpath[q]=gpidx[(grade[i]*5+grade[j])*5+grade[k]];
      ++q;
    }
  }
  for(int j=0;j<16;++j) for(int k=0;k<16;++k){
    int mj=bladeOf[j], mk=bladeOf[k];
    int cj=15^mj, ck=15^mk;
    if(!(cj&ck)){
      int r=mj&mk; int i=idxOf[r];
      int par = swap_par(mj,15^mj) ^ swap_par(mk,15^mk) ^ swap_par(cj,ck) ^ swap_par(r,15^r);
      t.qi[q]=i; t.qj[q]=j; t.qk[q]=k;
      t.qs[q] = par ? -1.0f : 1.0f;
      t.qgp[q]=0;
      t.qpath[q]=jpidx[(grade[i]*5+grade[j])*5+grade[k]];
      ++q;
    }
  }
  t.nq=q;
  return t;
}

constexpr GATab TAB = make_tab();
static_assert(TAB.nq == NQ, "nonzero count mismatch");
static_assert(TAB.ngp > 0 && TAB.njp > 0, "path counts");
constexpr int NGPC = TAB.ngp;
constexpr int NJPC = TAB.njp;
constexpr int GR[16] = {0,1,1,1,1,2,2,2,2,2,2,3,3,3,3,4};

// ---------------- prep kernels ----------------
// repack lin_weight (128,64,5) -> wrp[i][n][12]:
//   s in [0,5):  w1 grade s for output channel n      (o = n)
//   s in [5,10): w2 grade s-5 for output channel n+64 (o = 64+n)
//   s in [10,12): pad (keeps per-(i,n) record 48 B -> 16B-aligned f4 loads)
__global__ void prep_wrp(const float* __restrict__ linw, float* __restrict__ wrp){
  int t = blockIdx.x*blockDim.x + threadIdx.x;
  if(t < 64*64*12){
    int s = t % 12;
    int n = (t/12) & 63;
    int i = t/(12*64);
    float v = 0.f;
    if(s < 5)       v = linw[(n*64 + i)*5 + s];
    else if(s < 10) v = linw[((64+n)*64 + i)*5 + (s-5)];
    wrp[t] = v;
  }
}

// coef[q][n] = sign_q * (gp? gpw[n][path] : jpw[n][path]);  fully unrolled -> TAB folds
__global__ void prep_coef(const float* __restrict__ gpw, const float* __restrict__ jpw,
                          float* __restrict__ coef){
  int n = threadIdx.x; // blockDim = 64, grid = 1
  #pragma unroll
  for(int q=0;q<NQ;++q){
    float w = TAB.qgp[q] ? gpw[n*NGPC + TAB.qpath[q]] : jpw[n*NJPC + TAB.qpath[q]];
    coef[q*64 + n] = TAB.qs[q]*w;
  }
}

// ---------------- main fused kernel ----------------
// lane = channel n (0..63); each wave handles NB=2 batch elements per pass.
// NB=2 keeps y1/y2/acc live set at 96 floats -> no scratch spills at 128 VGPR.
__global__ __launch_bounds__(256, 4)
void main_k(const float* __restrict__ x, const float* __restrict__ coef,
            const float* __restrict__ wrp, float* __restrict__ out, int B){
  __shared__ float xl[4][NB][64][16];   // 32 KB -> 4 blocks/CU (VGPR-limited), 16 waves/CU
  const int lane = threadIdx.x & 63;
  const int wv   = threadIdx.x >> 6;
  const int n    = lane;

  for(int base = blockIdx.x*(4*NB); base < B; base += gridDim.x*(4*NB)){
    const int b0 = base + wv*NB;

    // ---- stage x for this wave's NB batch elements (streamed once -> nontemporal) ----
    #pragma unroll
    for(int t=0;t<NB;++t){
      int bb = b0 + t;
      if(bb < B){
        const f4* src = (const f4*)(x + ((long)bb*64 + lane)*16);
        f4 a0=__builtin_nontemporal_load(src+0);
        f4 a1=__builtin_nontemporal_load(src+1);
        f4 a2=__builtin_nontemporal_load(src+2);
        f4 a3=__builtin_nontemporal_load(src+3);
        f4* dst = (f4*)(&xl[wv][t][lane][0]);
        dst[0]=a0; dst[1]=a1; dst[2]=a2; dst[3]=a3;
      }
    }
    // (no __syncthreads needed: each wave writes/reads only its own slot,
    //  compiler inserts lgkmcnt waits for within-wave LDS ordering)

    // ---- linear phase: y1[v] = sum_i w1[g(v)]*x[i][v], y2 likewise ----
    float y1[NB][16]; float y2[NB][16];
    #pragma unroll
    for(int t=0;t<NB;++t)
      #pragma unroll
      for(int v=0;v<16;++v){ y1[t][v]=0.f; y2[t][v]=0.f; }

    #pragma unroll 4
    for(int i=0;i<64;++i){
      const f4* wp = (const f4*)(wrp + (i*64 + n)*12);
      f4 wa = wp[0], wb = wp[1], wc = wp[2];
      float w1[5] = {wa[0],wa[1],wa[2],wa[3],wb[0]};
      float w2[5] = {wb[1],wb[2],wb[3],wc[0],wc[1]};
      #pragma unroll
      for(int t=0;t<NB;++t){
        const f4* xs = (const f4*)(&xl[wv][t][i][0]);
        f4 xa=xs[0], xb=xs[1], xc=xs[2], xd=xs[3];
        float xv[16]={xa[0],xa[1],xa[2],xa[3], xb[0],xb[1],xb[2],xb[3],
                      xc[0],xc[1],xc[2],xc[3], xd[0],xd[1],xd[2],xd[3]};
        #pragma unroll
        for(int v=0;v<16;++v){
          y1[t][v] = fmaf(w1[GR[v]], xv[v], y1[t][v]);
          y2[t][v] = fmaf(w2[GR[v]], xv[v], y2[t][v]);
        }
      }
    }

    // ---- bilinear phase: acc[i] = y2[i] + sum_q coef[n,q]*y1[j_q]*y2[k_q] ----
    float acc[NB][16];
    #pragma unroll
    for(int t=0;t<NB;++t)
      #pragma unroll
      for(int v=0;v<16;++v) acc[t][v]=y2[t][v];

    #pragma unroll
    for(int q=0;q<NQ;++q){
      float c = coef[q*64 + n];
      #pragma unroll
      for(int t=0;t<NB;++t){
        acc[t][TAB.qi[q]] = fmaf(c, y1[t][TAB.qj[q]]*y2[t][TAB.qk[q]], acc[t][TAB.qi[q]]);
      }
    }

    // ---- store (streamed once -> nontemporal, avoid RFO/L2 pollution) ----
    #pragma unroll
    for(int t=0;t<NB;++t){
      int bb = b0 + t;
      if(bb < B){
        f4* op = (f4*)(out + ((long)bb*64 + n)*16);
        #pragma unroll
        for(int r=0;r<4;++r){
          f4 o; o[0]=acc[t][4*r]; o[1]=acc[t][4*r+1]; o[2]=acc[t][4*r+2]; o[3]=acc[t][4*r+3];
          __builtin_nontemporal_store(o, op+r);
        }
      }
    }
  }
}

extern "C" void kernel_launch(void* const* d_in, const int* in_sizes, int n_in,
                              void* d_out, int out_size, void* d_ws, size_t ws_size,
                              hipStream_t stream){
  const float* x    = (const float*)d_in[0];
  const float* gpw  = (const float*)d_in[1];
  const float* jpw  = (const float*)d_in[2];
  const float* linw = (const float*)d_in[3];
  float* outp = (float*)d_out;

  float* wrp  = (float*)d_ws;          // 64*64*12 floats = 192 KB
  float* coef = wrp + 64*64*12;        // NQ*64 floats ≈ 68 KB

  int B = in_sizes[0] / (64*16);

  prep_wrp <<<192, 256, 0, stream>>>(linw, wrp);
  prep_coef<<<1,   64,  0, stream>>>(gpw, jpw, coef);
  main_k   <<<4096, 256, 0, stream>>>(x, coef, wrp, outp, B);
}

// Round 2
// 1714.619 us; speedup vs baseline: 2.4312x; 2.4312x over previous
//
#include <hip/hip_runtime.h>

#define NQ 273
#define NB 2

typedef float f4 __attribute__((ext_vector_type(4)));

// ---------------- compile-time GA tables (Cl(3,0,1) PGA, 16 blades) ----------------
struct GATab {
  int qi[NQ]; int qj[NQ]; int qk[NQ];
  float qs[NQ];
  int qgp[NQ];
  int qpath[NQ];
  int ngp, njp, nq;
};

constexpr int popc4(int m){ int c=0; for(int b=0;b<5;++b) c+=(m>>b)&1; return c; }
constexpr int swap_par(int a,int b){ int s=0; a>>=1; while(a){ s+=popc4(a&b); a>>=1; } return s&1; }

constexpr GATab make_tab(){
  GATab t{};
  int bladeOf[16]={}; int idxOf[16]={};
  { int p=0;
    for(int g=0; g<=4; ++g)
      for(int m=0; m<16; ++m)
        if(popc4(m)==g){ bladeOf[p]=m; idxOf[m]=p; ++p; }
  }
  int grade[16]={};
  for(int j=0;j<16;++j) grade[j]=popc4(bladeOf[j]);
  bool gpp[125]={}; bool jpp[125]={};
  for(int j=0;j<16;++j) for(int k=0;k<16;++k){
    int mj=bladeOf[j], mk=bladeOf[k];
    if(!(mj&mk&1)){ int i=idxOf[mj^mk]; gpp[(grade[i]*5+grade[j])*5+grade[k]]=true; }
    int cj=15^mj, ck=15^mk;
    if(!(cj&ck)){ int r=mj&mk; int i=idxOf[r]; jpp[(grade[i]*5+grade[j])*5+grade[k]]=true; }
  }
  int gpidx[125]={}; int jpidx[125]={};
  { int c=0; for(int u=0;u<125;++u){ gpidx[u] = gpp[u]? c++ : -1; } t.ngp=c; }
  { int c=0; for(int u=0;u<125;++u){ jpidx[u] = jpp[u]? c++ : -1; } t.njp=c; }
  int q=0;
  for(int j=0;j<16;++j) for(int k=0;k<16;++k){
    int mj=bladeOf[j], mk=bladeOf[k];
    if(!(mj&mk&1)){
      int i=idxOf[mj^mk];
      t.qi[q]=i; t.qj[q]=j; t.qk[q]=k;
      t.qs[q] = swap_par(mj,mk) ? -1.0f : 1.0f;
      t.qgp[q]=1;
      t.qpath[q]=gpidx[(grade[i]*5+grade[j])*5+grade[k]];
      ++q;
    }
  }
  for(int j=0;j<16;++j) for(int k=0;k<16;++k){
    int mj=bladeOf[j], mk=bladeOf[k];
    int cj=15^mj, ck=15^mk;
    if(!(cj&ck)){
      int r=mj&mk; int i=idxOf[r];
      int par = swap_par(mj,15^mj) ^ swap_par(mk,15^mk) ^ swap_par(cj,ck) ^ swap_par(r,15^r);
      t.qi[q]=i; t.qj[q]=j; t.qk[q]=k;
      t.qs[q] = par ? -1.0f : 1.0f;
      t.qgp[q]=0;
      t.qpath[q]=jpidx[(grade[i]*5+grade[j])*5+grade[k]];
      ++q;
    }
  }
  t.nq=q;
  return t;
}

constexpr GATab TAB = make_tab();
static_assert(TAB.nq == NQ, "nonzero count mismatch");
static_assert(TAB.ngp > 0 && TAB.njp > 0, "path counts");
constexpr int NGPC = TAB.ngp;
constexpr int NJPC = TAB.njp;
constexpr int GR[16] = {0,1,1,1,1,2,2,2,2,2,2,3,3,3,3,4};

// ---------------- prep kernels ----------------
// repack lin_weight (128,64,5) -> wrp[i][n][12]:
//   s in [0,5):  w1 grade s for output channel n      (o = n)
//   s in [5,10): w2 grade s-5 for output channel n+64 (o = 64+n)
//   s in [10,12): pad (keeps per-(i,n) record 48 B -> 16B-aligned f4 loads)
__global__ void prep_wrp(const float* __restrict__ linw, float* __restrict__ wrp){
  int t = blockIdx.x*blockDim.x + threadIdx.x;
  if(t < 64*64*12){
    int s = t % 12;
    int n = (t/12) & 63;
    int i = t/(12*64);
    float v = 0.f;
    if(s < 5)       v = linw[(n*64 + i)*5 + s];
    else if(s < 10) v = linw[((64+n)*64 + i)*5 + (s-5)];
    wrp[t] = v;
  }
}

// coef[q][n] = sign_q * (gp? gpw[n][path] : jpw[n][path]);  fully unrolled -> TAB folds
__global__ void prep_coef(const float* __restrict__ gpw, const float* __restrict__ jpw,
                          float* __restrict__ coef){
  int n = threadIdx.x; // blockDim = 64, grid = 1
  #pragma unroll
  for(int q=0;q<NQ;++q){
    float w = TAB.qgp[q] ? gpw[n*NGPC + TAB.qpath[q]] : jpw[n*NJPC + TAB.qpath[q]];
    coef[q*64 + n] = TAB.qs[q]*w;
  }
}

// ---------------- main fused kernel ----------------
// lane = channel n (0..63); each wave handles NB=2 batch elements per pass.
// NB=2 keeps y1/y2/acc live set ~110 floats; __launch_bounds__(256,2) empirically
// yields the 128-VGPR tier on this toolchain (NOT (256,4): that clamps to 64 -> spills).
// LDS 32 KB/block -> 4 blocks/CU (VGPR-limited at 128), 16 waves/CU.
__global__ __launch_bounds__(256, 2)
void main_k(const float* __restrict__ x, const float* __restrict__ coef,
            const float* __restrict__ wrp, float* __restrict__ out, int B){
  __shared__ float xl[4][NB][64][16];   // 32 KB
  const int lane = threadIdx.x & 63;
  const int wv   = threadIdx.x >> 6;
  const int n    = lane;

  for(int base = blockIdx.x*(4*NB); base < B; base += gridDim.x*(4*NB)){
    const int b0 = base + wv*NB;

    // ---- stage x for this wave's NB batch elements (streamed once -> nontemporal) ----
    #pragma unroll
    for(int t=0;t<NB;++t){
      int bb = b0 + t;
      if(bb < B){
        const f4* src = (const f4*)(x + ((long)bb*64 + lane)*16);
        f4 a0=__builtin_nontemporal_load(src+0);
        f4 a1=__builtin_nontemporal_load(src+1);
        f4 a2=__builtin_nontemporal_load(src+2);
        f4 a3=__builtin_nontemporal_load(src+3);
        f4* dst = (f4*)(&xl[wv][t][lane][0]);
        dst[0]=a0; dst[1]=a1; dst[2]=a2; dst[3]=a3;
      }
    }
    // (no __syncthreads needed: each wave writes/reads only its own slot,
    //  compiler inserts lgkmcnt waits for within-wave LDS ordering)

    // ---- linear phase: y1[v] = sum_i w1[g(v)]*x[i][v], y2 likewise ----
    float y1[NB][16]; float y2[NB][16];
    #pragma unroll
    for(int t=0;t<NB;++t)
      #pragma unroll
      for(int v=0;v<16;++v){ y1[t][v]=0.f; y2[t][v]=0.f; }

    #pragma unroll 2
    for(int i=0;i<64;++i){
      const f4* wp = (const f4*)(wrp + (i*64 + n)*12);
      f4 wa = wp[0], wb = wp[1], wc = wp[2];
      float w1[5] = {wa[0],wa[1],wa[2],wa[3],wb[0]};
      float w2[5] = {wb[1],wb[2],wb[3],wc[0],wc[1]};
      #pragma unroll
      for(int t=0;t<NB;++t){
        const f4* xs = (const f4*)(&xl[wv][t][i][0]);
        f4 xa=xs[0], xb=xs[1], xc=xs[2], xd=xs[3];
        float xv[16]={xa[0],xa[1],xa[2],xa[3], xb[0],xb[1],xb[2],xb[3],
                      xc[0],xc[1],xc[2],xc[3], xd[0],xd[1],xd[2],xd[3]};
        #pragma unroll
        for(int v=0;v<16;++v){
          y1[t][v] = fmaf(w1[GR[v]], xv[v], y1[t][v]);
          y2[t][v] = fmaf(w2[GR[v]], xv[v], y2[t][v]);
        }
      }
    }

    // ---- bilinear phase: acc[i] = y2[i] + sum_q coef[n,q]*y1[j_q]*y2[k_q] ----
    float acc[NB][16];
    #pragma unroll
    for(int t=0;t<NB;++t)
      #pragma unroll
      for(int v=0;v<16;++v) acc[t][v]=y2[t][v];

    #pragma unroll
    for(int q=0;q<NQ;++q){
      float c = coef[q*64 + n];
      #pragma unroll
      for(int t=0;t<NB;++t){
        acc[t][TAB.qi[q]] = fmaf(c, y1[t][TAB.qj[q]]*y2[t][TAB.qk[q]], acc[t][TAB.qi[q]]);
      }
    }

    // ---- store (streamed once -> nontemporal, avoid RFO/L2 pollution) ----
    #pragma unroll
    for(int t=0;t<NB;++t){
      int bb = b0 + t;
      if(bb < B){
        f4* op = (f4*)(out + ((long)bb*64 + n)*16);
        #pragma unroll
        for(int r=0;r<4;++r){
          f4 o; o[0]=acc[t][4*r]; o[1]=acc[t][4*r+1]; o[2]=acc[t][4*r+2]; o[3]=acc[t][4*r+3];
          __builtin_nontemporal_store(o, op+r);
        }
      }
    }
  }
}

extern "C" void kernel_launch(void* const* d_in, const int* in_sizes, int n_in,
                              void* d_out, int out_size, void* d_ws, size_t ws_size,
                              hipStream_t stream){
  const float* x    = (const float*)d_in[0];
  const float* gpw  = (const float*)d_in[1];
  const float* jpw  = (const float*)d_in[2];
  const float* linw = (const float*)d_in[3];
  float* outp = (float*)d_out;

  float* wrp  = (float*)d_ws;          // 64*64*12 floats = 192 KB
  float* coef = wrp + 64*64*12;        // NQ*64 floats ≈ 68 KB

  int B = in_sizes[0] / (64*16);

  prep_wrp <<<192, 256, 0, stream>>>(linw, wrp);
  prep_coef<<<1,   64,  0, stream>>>(gpw, jpw, coef);
  main_k   <<<4096, 256, 0, stream>>>(x, coef, wrp, outp, B);
}

// Round 3
// 993.112 us; speedup vs baseline: 4.1975x; 1.7265x over previous
//
#include <hip/hip_runtime.h>

#define NQ 273
#define NB 2

typedef float f4 __attribute__((ext_vector_type(4)));

// ---------------- compile-time GA tables (Cl(3,0,1) PGA, 16 blades) ----------------
struct GATab {
  int qi[NQ]; int qj[NQ]; int qk[NQ];
  float qs[NQ];
  int qgp[NQ];
  int qpath[NQ];
  int ngp, njp, nq;
};

constexpr int popc4(int m){ int c=0; for(int b=0;b<5;++b) c+=(m>>b)&1; return c; }
constexpr int swap_par(int a,int b){ int s=0; a>>=1; while(a){ s+=popc4(a&b); a>>=1; } return s&1; }

constexpr GATab make_tab(){
  GATab t{};
  int bladeOf[16]={}; int idxOf[16]={};
  { int p=0;
    for(int g=0; g<=4; ++g)
      for(int m=0; m<16; ++m)
        if(popc4(m)==g){ bladeOf[p]=m; idxOf[m]=p; ++p; }
  }
  int grade[16]={};
  for(int j=0;j<16;++j) grade[j]=popc4(bladeOf[j]);
  bool gpp[125]={}; bool jpp[125]={};
  for(int j=0;j<16;++j) for(int k=0;k<16;++k){
    int mj=bladeOf[j], mk=bladeOf[k];
    if(!(mj&mk&1)){ int i=idxOf[mj^mk]; gpp[(grade[i]*5+grade[j])*5+grade[k]]=true; }
    int cj=15^mj, ck=15^mk;
    if(!(cj&ck)){ int r=mj&mk; int i=idxOf[r]; jpp[(grade[i]*5+grade[j])*5+grade[k]]=true; }
  }
  int gpidx[125]={}; int jpidx[125]={};
  { int c=0; for(int u=0;u<125;++u){ gpidx[u] = gpp[u]? c++ : -1; } t.ngp=c; }
  { int c=0; for(int u=0;u<125;++u){ jpidx[u] = jpp[u]? c++ : -1; } t.njp=c; }
  int q=0;
  for(int j=0;j<16;++j) for(int k=0;k<16;++k){
    int mj=bladeOf[j], mk=bladeOf[k];
    if(!(mj&mk&1)){
      int i=idxOf[mj^mk];
      t.qi[q]=i; t.qj[q]=j; t.qk[q]=k;
      t.qs[q] = swap_par(mj,mk) ? -1.0f : 1.0f;
      t.qgp[q]=1;
      t.qpath[q]=gpidx[(grade[i]*5+grade[j])*5+grade[k]];
      ++q;
    }
  }
  for(int j=0;j<16;++j) for(int k=0;k<16;++k){
    int mj=bladeOf[j], mk=bladeOf[k];
    int cj=15^mj, ck=15^mk;
    if(!(cj&ck)){
      int r=mj&mk; int i=idxOf[r];
      int par = swap_par(mj,15^mj) ^ swap_par(mk,15^mk) ^ swap_par(cj,ck) ^ swap_par(r,15^r);
      t.qi[q]=i; t.qj[q]=j; t.qk[q]=k;
      t.qs[q] = par ? -1.0f : 1.0f;
      t.qgp[q]=0;
      t.qpath[q]=jpidx[(grade[i]*5+grade[j])*5+grade[k]];
      ++q;
    }
  }
  t.nq=q;
  return t;
}

constexpr GATab TAB = make_tab();
static_assert(TAB.nq == NQ, "nonzero count mismatch");
static_assert(TAB.ngp > 0 && TAB.njp > 0, "path counts");
constexpr int NGPC = TAB.ngp;
constexpr int NJPC = TAB.njp;
constexpr int GR[16] = {0,1,1,1,1,2,2,2,2,2,2,3,3,3,3,4};

// ---------------- prep kernels ----------------
// repack lin_weight (128,64,5) -> wrp[i][n][12]:
//   s in [0,5):  w1 grade s for output channel n      (o = n)
//   s in [5,10): w2 grade s-5 for output channel n+64 (o = 64+n)
//   s in [10,12): pad (keeps per-(i,n) record 48 B -> 16B-aligned f4 loads)
__global__ void prep_wrp(const float* __restrict__ linw, float* __restrict__ wrp){
  int t = blockIdx.x*blockDim.x + threadIdx.x;
  if(t < 64*64*12){
    int s = t % 12;
    int n = (t/12) & 63;
    int i = t/(12*64);
    float v = 0.f;
    if(s < 5)       v = linw[(n*64 + i)*5 + s];
    else if(s < 10) v = linw[((64+n)*64 + i)*5 + (s-5)];
    wrp[t] = v;
  }
}

// coef[q][n] = sign_q * (gp? gpw[n][path] : jpw[n][path]);  fully unrolled -> TAB folds
__global__ void prep_coef(const float* __restrict__ gpw, const float* __restrict__ jpw,
                          float* __restrict__ coef){
  int n = threadIdx.x; // blockDim = 64, grid = 1
  #pragma unroll
  for(int q=0;q<NQ;++q){
    float w = TAB.qgp[q] ? gpw[n*NGPC + TAB.qpath[q]] : jpw[n*NJPC + TAB.qpath[q]];
    coef[q*64 + n] = TAB.qs[q]*w;
  }
}

// ---------------- main fused kernel ----------------
// lane = channel n (0..63); each wave handles NB=2 batch elements per pass.
// NO second __launch_bounds__ arg: live set is y1+y2+acc = 96 floats plus
// staging/prefetch -> needs ~160-200 VGPRs. Capping at 128 ((256,2)) caused a
// ~48-float/lane spill per pass = ~3 GB of HBM scratch traffic AND scratch
// allocation capped occupancy at ~8 waves/CU anyway. Uncapped: zero spill at
// the same-or-better occupancy.
__global__ __launch_bounds__(256)
void main_k(const float* __restrict__ x, const float* __restrict__ coef,
            const float* __restrict__ wrp, float* __restrict__ out, int B){
  __shared__ float xl[4][NB][64][16];   // 32 KB
  const int lane = threadIdx.x & 63;
  const int wv   = threadIdx.x >> 6;
  const int n    = lane;

  for(int base = blockIdx.x*(4*NB); base < B; base += gridDim.x*(4*NB)){
    const int b0 = base + wv*NB;

    // ---- stage x for this wave's NB batch elements (streamed once -> nontemporal) ----
    #pragma unroll
    for(int t=0;t<NB;++t){
      int bb = b0 + t;
      if(bb < B){
        const f4* src = (const f4*)(x + ((long)bb*64 + lane)*16);
        f4 a0=__builtin_nontemporal_load(src+0);
        f4 a1=__builtin_nontemporal_load(src+1);
        f4 a2=__builtin_nontemporal_load(src+2);
        f4 a3=__builtin_nontemporal_load(src+3);
        f4* dst = (f4*)(&xl[wv][t][lane][0]);
        dst[0]=a0; dst[1]=a1; dst[2]=a2; dst[3]=a3;
      }
    }
    // (no __syncthreads needed: each wave writes/reads only its own slot,
    //  compiler inserts lgkmcnt waits for within-wave LDS ordering)

    // ---- linear phase: y1[v] = sum_i w1[g(v)]*x[i][v], y2 likewise ----
    float y1[NB][16]; float y2[NB][16];
    #pragma unroll
    for(int t=0;t<NB;++t)
      #pragma unroll
      for(int v=0;v<16;++v){ y1[t][v]=0.f; y2[t][v]=0.f; }

    #pragma unroll 2
    for(int i=0;i<64;++i){
      const f4* wp = (const f4*)(wrp + (i*64 + n)*12);
      f4 wa = wp[0], wb = wp[1], wc = wp[2];
      float w1[5] = {wa[0],wa[1],wa[2],wa[3],wb[0]};
      float w2[5] = {wb[1],wb[2],wb[3],wc[0],wc[1]};
      #pragma unroll
      for(int t=0;t<NB;++t){
        const f4* xs = (const f4*)(&xl[wv][t][i][0]);
        f4 xa=xs[0], xb=xs[1], xc=xs[2], xd=xs[3];
        float xv[16]={xa[0],xa[1],xa[2],xa[3], xb[0],xb[1],xb[2],xb[3],
                      xc[0],xc[1],xc[2],xc[3], xd[0],xd[1],xd[2],xd[3]};
        #pragma unroll
        for(int v=0;v<16;++v){
          y1[t][v] = fmaf(w1[GR[v]], xv[v], y1[t][v]);
          y2[t][v] = fmaf(w2[GR[v]], xv[v], y2[t][v]);
        }
      }
    }

    // ---- bilinear phase: acc[i] = y2[i] + sum_q coef[n,q]*y1[j_q]*y2[k_q] ----
    float acc[NB][16];
    #pragma unroll
    for(int t=0;t<NB;++t)
      #pragma unroll
      for(int v=0;v<16;++v) acc[t][v]=y2[t][v];

    const float* cp = coef + n;
    #pragma unroll
    for(int q=0;q<NQ;++q){
      float c = cp[q*64];
      #pragma unroll
      for(int t=0;t<NB;++t){
        acc[t][TAB.qi[q]] = fmaf(c, y1[t][TAB.qj[q]]*y2[t][TAB.qk[q]], acc[t][TAB.qi[q]]);
      }
    }

    // ---- store (streamed once -> nontemporal, avoid RFO/L2 pollution) ----
    #pragma unroll
    for(int t=0;t<NB;++t){
      int bb = b0 + t;
      if(bb < B){
        f4* op = (f4*)(out + ((long)bb*64 + n)*16);
        #pragma unroll
        for(int r=0;r<4;++r){
          f4 o; o[0]=acc[t][4*r]; o[1]=acc[t][4*r+1]; o[2]=acc[t][4*r+2]; o[3]=acc[t][4*r+3];
          __builtin_nontemporal_store(o, op+r);
        }
      }
    }
  }
}

extern "C" void kernel_launch(void* const* d_in, const int* in_sizes, int n_in,
                              void* d_out, int out_size, void* d_ws, size_t ws_size,
                              hipStream_t stream){
  const float* x    = (const float*)d_in[0];
  const float* gpw  = (const float*)d_in[1];
  const float* jpw  = (const float*)d_in[2];
  const float* linw = (const float*)d_in[3];
  float* outp = (float*)d_out;

  float* wrp  = (float*)d_ws;          // 64*64*12 floats = 192 KB
  float* coef = wrp + 64*64*12;        // NQ*64 floats ≈ 68 KB

  int B = in_sizes[0] / (64*16);

  prep_wrp <<<192, 256, 0, stream>>>(linw, wrp);
  prep_coef<<<1,   64,  0, stream>>>(gpw, jpw, coef);
  main_k   <<<4096, 256, 0, stream>>>(x, coef, wrp, outp, B);
}